// Round 11
// baseline (1763.371 us; speedup 1.0000x reference)
//
#include <hip/hip_runtime.h>
#include <math.h>

#define NV 163842
#define NE 983052
#define NBE 3841   // ceil(NE/256)
#define CAP 32     // fixed CSR row capacity (max in-degree; Poisson(6) tail ~1e-13)
#define CAPSH 5

// order-preserving float->uint transform (descending top-k: larger value -> larger key)
static __device__ __forceinline__ unsigned ordf(float f){
  unsigned u = __float_as_uint(f);
  return (u & 0x80000000u) ? ~u : (u | 0x80000000u);
}

// cooperative (256 threads, blockDim=256): find bin (descending key order) where the
// cumulative count crosses `rank`, two-level coarse[256] -> fine[65536].
// Returns bin; *rres = rank within bin. Deterministic; callable multiple times per kernel.
__device__ int derive_level(const int* __restrict__ coarse, const int* __restrict__ fine,
                            int rank, int* rres){
  __shared__ int sh[256];
  __shared__ int s_c, s_r, s_b, s_q;
  int t = threadIdx.x;
  int v = coarse[255-t];
  sh[t]=v; __syncthreads();
  for(int o=1;o<256;o<<=1){ int tv=(t>=o)?sh[t-o]:0; __syncthreads(); sh[t]+=tv; __syncthreads(); }
  int excl = sh[t]-v;
  if(v>0 && excl<rank && rank<=excl+v){ s_c=255-t; s_r=rank-excl; }
  __syncthreads();
  int cc=s_c, rr=s_r;
  __syncthreads();
  v = fine[(cc<<8)+(255-t)];
  sh[t]=v; __syncthreads();
  for(int o=1;o<256;o<<=1){ int tv=(t>=o)?sh[t-o]:0; __syncthreads(); sh[t]+=tv; __syncthreads(); }
  excl = sh[t]-v;
  if(v>0 && excl<rr && rr<=excl+v){ s_b=(cc<<8)+(255-t); s_q=rr-excl; }
  __syncthreads();
  int bin=s_b; *rres=s_q;
  __syncthreads();
  return bin;
}

// ---------------- CSR build (fixed capacity; fill+degree in ONE scatter pass) ----------------

__global__ void csr_fill0(const int* __restrict__ ei, int* __restrict__ deg,
                          int* __restrict__ csr){
  int e = blockIdx.x*256 + threadIdx.x;
  if(e>=NE) return;
  int s = ei[e], d = ei[NE+e];
  int slot = atomicAdd(&deg[d], 1);
  if(slot < CAP) csr[((size_t)d<<CAPSH)+slot] = s;
}

// layer l<3: rebuild next-layer CSR straight from the ORIGINAL edge list through the
// orig-space survival map (composed across layers by compact) — no edge-list materialization
__global__ void csr_build_next(const int* __restrict__ ei, const int* __restrict__ map,
                               int* __restrict__ deg_next, int* __restrict__ csr_next){
  int e = blockIdx.x*256 + threadIdx.x;
  if(e>=NE) return;
  int ns = map[ei[e]];
  if(ns<0) return;
  int nd = map[ei[NE+e]];
  if(nd<0) return;
  int slot = atomicAdd(&deg_next[nd], 1);
  if(slot < CAP) csr_next[((size_t)nd<<CAPSH)+slot] = ns;
}

// ---------------- aggregation (gather, float4, norms inline) ----------------

// layer 0: h read directly (x)
__global__ void csr_gather4(const float* __restrict__ h, const int* __restrict__ degi,
                            const int* __restrict__ csr, float* __restrict__ g,
                            int n, int Fi, int qshift){
  long long t = (long long)blockIdx.x*blockDim.x + threadIdx.x;
  int d = (int)(t >> qshift);
  if(d>=n) return;
  int q = ((int)t & ((1<<qshift)-1)) << 2;
  int deg = degi[d];
  int dc = deg < CAP ? deg : CAP;
  float di = rsqrtf((float)deg + 1.0f);
  const int* row = csr + ((size_t)d<<CAPSH);
  float4 hv = *(const float4*)(h + (size_t)d*Fi + q);
  float4 acc = make_float4(hv.x*di, hv.y*di, hv.z*di, hv.w*di);
  for(int j=0;j<dc;j++){
    int s = row[j];
    float ds = rsqrtf((float)degi[s] + 1.0f);
    float4 hs = *(const float4*)(h + (size_t)s*Fi + q);
    acc.x = fmaf(hs.x, ds, acc.x);
    acc.y = fmaf(hs.y, ds, acc.y);
    acc.z = fmaf(hs.z, ds, acc.z);
    acc.w = fmaf(hs.w, ds, acc.w);
  }
  *(float4*)(g + (size_t)d*Fi + q) = make_float4(acc.x*di, acc.y*di, acc.z*di, acc.w*di);
}

// layers 1-3: pooled input read via indirection hprev[oldidx[.]]*scprev[oldidx[.]]
__global__ void csr_gather4_ind(const float* __restrict__ hprev, const float* __restrict__ scprev,
                                const int* __restrict__ oldidx, const int* __restrict__ degi,
                                const int* __restrict__ csr, float* __restrict__ g,
                                int n, int Fi, int qshift){
  long long t = (long long)blockIdx.x*blockDim.x + threadIdx.x;
  int d = (int)(t >> qshift);
  if(d>=n) return;
  int q = ((int)t & ((1<<qshift)-1)) << 2;
  int deg = degi[d];
  int dc = deg < CAP ? deg : CAP;
  float di = rsqrtf((float)deg + 1.0f);
  int od = oldidx[d];
  float wd = scprev[od]*di;
  const int* row = csr + ((size_t)d<<CAPSH);
  float4 hv = *(const float4*)(hprev + (size_t)od*Fi + q);
  float4 acc = make_float4(hv.x*wd, hv.y*wd, hv.z*wd, hv.w*wd);
  for(int j=0;j<dc;j++){
    int s = row[j];
    int os = oldidx[s];
    float ws = scprev[os]*rsqrtf((float)degi[s] + 1.0f);
    float4 hs = *(const float4*)(hprev + (size_t)os*Fi + q);
    acc.x = fmaf(hs.x, ws, acc.x);
    acc.y = fmaf(hs.y, ws, acc.y);
    acc.z = fmaf(hs.z, ws, acc.z);
    acc.w = fmaf(hs.w, ws, acc.w);
  }
  *(float4*)(g + (size_t)d*Fi + q) = make_float4(acc.x*di, acc.y*di, acc.z*di, acc.w*di);
}

// ---------------- LDS-tiled, register-tiled fused dense (verified rounds 8-10) ----------------
__global__ void matmul_relu_score_t(const float* __restrict__ h, const float* __restrict__ W,
                                    const float* __restrict__ b, const float* __restrict__ p,
                                    float* __restrict__ out, float* __restrict__ score,
                                    int n, int Fi, int Fo, int foshf, int BM, int qsh){
  __shared__ float lh[4096];     // [BM][Fi], BM*Fi <= 4096
  __shared__ float pn_sh;
  int tid = threadIdx.x;
  if(tid < 64){
    float s=0.f;
    for(int f=tid; f<Fo; f+=64) s += p[f]*p[f];
    for(int o=32;o;o>>=1) s += __shfl_down(s,o,64);
    if(tid==0) pn_sh = rsqrtf(s);
  }
  int rb = blockIdx.x*BM;
  int fq = Fi>>2;
  int total_q = BM*fq;
  for(int idx=tid; idx<total_q; idx+=256){
    int row = idx>>qsh, q = idx & (fq-1);
    float4 v = make_float4(0.f,0.f,0.f,0.f);
    if(rb+row < n) v = *(const float4*)(h + (size_t)(rb+row)*Fi + q*4);
    *(float4*)(lh + (size_t)row*Fi + q*4) = v;
  }
  __syncthreads();
  int CG = Fo>>2;
  int colg = tid & (CG-1);
  int rowg = tid >> (foshf-2);
  int r0 = rowg<<3;
  int c0 = colg<<2;
  float acc[8][4];
  #pragma unroll
  for(int j=0;j<8;j++){ acc[j][0]=0.f; acc[j][1]=0.f; acc[j][2]=0.f; acc[j][3]=0.f; }
  for(int i=0;i<Fi;i+=4){
    const float* Wp = W + (size_t)i*Fo + c0;
    float4 w0 = *(const float4*)(Wp);
    float4 w1 = *(const float4*)(Wp + Fo);
    float4 w2 = *(const float4*)(Wp + 2*Fo);
    float4 w3 = *(const float4*)(Wp + 3*Fo);
    const float* lp = lh + (size_t)r0*Fi + i;
    #pragma unroll
    for(int j=0;j<8;j++){
      float4 hv = *(const float4*)(lp + (size_t)j*Fi);
      acc[j][0] = fmaf(hv.x,w0.x, fmaf(hv.y,w1.x, fmaf(hv.z,w2.x, fmaf(hv.w,w3.x, acc[j][0]))));
      acc[j][1] = fmaf(hv.x,w0.y, fmaf(hv.y,w1.y, fmaf(hv.z,w2.y, fmaf(hv.w,w3.y, acc[j][1]))));
      acc[j][2] = fmaf(hv.x,w0.z, fmaf(hv.y,w1.z, fmaf(hv.z,w2.z, fmaf(hv.w,w3.z, acc[j][2]))));
      acc[j][3] = fmaf(hv.x,w0.w, fmaf(hv.y,w1.w, fmaf(hv.z,w2.w, fmaf(hv.w,w3.w, acc[j][3]))));
    }
  }
  float4 bc = *(const float4*)(b + c0);
  float4 pc = *(const float4*)(p + c0);
  int width = CG;   // <= 64 always (Fo <= 256)
  #pragma unroll
  for(int j=0;j<8;j++){
    int row = rb + r0 + j;
    float v0 = fmaxf(acc[j][0]+bc.x, 0.f);
    float v1 = fmaxf(acc[j][1]+bc.y, 0.f);
    float v2 = fmaxf(acc[j][2]+bc.z, 0.f);
    float v3 = fmaxf(acc[j][3]+bc.w, 0.f);
    if(row < n) *(float4*)(out + (size_t)row*Fo + c0) = make_float4(v0,v1,v2,v3);
    float sc = v0*pc.x + v1*pc.y + v2*pc.z + v3*pc.w;
    for(int o=width>>1; o; o>>=1) sc += __shfl_down(sc, o, width);
    if(colg==0 && row<n) score[row] = tanhf(sc * pn_sh);
  }
}

// ---------------- grid-wide two-level 16-bit top-k select (coarse+fine histograms) ----------------
__global__ void hist_hi(const float* __restrict__ score, int n,
                        int* __restrict__ fine, int* __restrict__ coarse){
  int T = gridDim.x*blockDim.x;
  int lane = threadIdx.x&63;
  for(int base=0; base<n; base+=T){
    int i = base + blockIdx.x*blockDim.x + threadIdx.x;
    bool act = i<n;
    unsigned key = act ? (ordf(score[i])>>16) : 0u;
    unsigned long long eq = __ballot(act);
    #pragma unroll
    for(int bit=0;bit<16;bit++){
      unsigned long long bb = __ballot(act && ((key>>bit)&1u));
      eq &= ((key>>bit)&1u) ? bb : ~bb;
    }
    if(act){
      int lead = __ffsll(eq)-1;
      if(lane==lead){
        int c = __popcll(eq);
        atomicAdd(&fine[key], c);
        atomicAdd(&coarse[key>>8], c);
      }
    }
  }
}

// derive hi-bin in-block from completed hi histograms, then histogram lo 16 bits of matches
__global__ void hist_lo(const float* __restrict__ score, int n, int k,
                        const int* __restrict__ ch, const int* __restrict__ fh,
                        int* __restrict__ fine, int* __restrict__ coarse){
  int r1;
  unsigned hi = (unsigned)derive_level(ch, fh, k, &r1);
  int T = gridDim.x*blockDim.x;
  int lane = threadIdx.x&63;
  for(int base=0; base<n; base+=T){
    int i = base + blockIdx.x*blockDim.x + threadIdx.x;
    unsigned o = (i<n) ? ordf(score[i]) : 0u;
    bool act = (i<n) && ((o>>16)==hi);
    unsigned key = o & 0xFFFFu;
    unsigned long long eq = __ballot(act);
    #pragma unroll
    for(int bit=0;bit<16;bit++){
      unsigned long long bb = __ballot(act && ((key>>bit)&1u));
      eq &= ((key>>bit)&1u) ? bb : ~bb;
    }
    if(act){
      int lead = __ffsll(eq)-1;
      if(lane==lead){
        int c = __popcll(eq);
        atomicAdd(&fine[key], c);
        atomicAdd(&coarse[key>>8], c);
      }
    }
  }
}

// ---------------- selection compaction (threshold derived in-block) ----------------

__global__ void sel_blockcount(const float* __restrict__ score, int n, int k,
                               const int* __restrict__ ch, const int* __restrict__ fh,
                               const int* __restrict__ cl, const int* __restrict__ fl,
                               int* __restrict__ blkGt, int* __restrict__ blkEq){
  int r1, q;
  int hi = derive_level(ch, fh, k, &r1);
  int lo = derive_level(cl, fl, r1, &q);
  unsigned vthr = ((unsigned)hi<<16)|(unsigned)lo;
  int i = blockIdx.x*256 + threadIdx.x;
  int gt=0, eq=0;
  if(i<n){ unsigned o=ordf(score[i]); gt = (o>vthr); eq = (o==vthr); }
  unsigned long long bg=__ballot(gt), be=__ballot(eq);
  __shared__ int sg[4], se[4];
  int lane=threadIdx.x&63, w=threadIdx.x>>6;
  if(lane==0){ sg[w]=__popcll(bg); se[w]=__popcll(be); }
  __syncthreads();
  if(threadIdx.x==0){
    int g=0,e=0;
    for(int j=0;j<4;j++){ g+=sg[j]; e+=se[j]; }
    blkGt[blockIdx.x]=g; blkEq[blockIdx.x]=e;
  }
}

// selects top-k set; writes oldidx (new->old) AND composes the orig-space survival map
__global__ void compact(const float* __restrict__ score, int n, int k,
                        const int* __restrict__ ch, const int* __restrict__ fh,
                        const int* __restrict__ cl, const int* __restrict__ fl,
                        const int* __restrict__ blkGt, const int* __restrict__ blkEq,
                        int* __restrict__ oldidx, int* __restrict__ map,
                        const int* __restrict__ ofc, int* __restrict__ ofn, int is_l0){
  int r1, q;
  int hi = derive_level(ch, fh, k, &r1);
  int lo = derive_level(cl, fl, r1, &q);
  unsigned vthr = ((unsigned)hi<<16)|(unsigned)lo;
  __shared__ int s_bg, s_be;
  {
    int pg=0, pe=0;
    for(int j=threadIdx.x; j<(int)blockIdx.x; j+=256){ pg+=blkGt[j]; pe+=blkEq[j]; }
    for(int o=32;o;o>>=1){ pg+=__shfl_down(pg,o,64); pe+=__shfl_down(pe,o,64); }
    __shared__ int sgp[4], sep[4];
    int lane=threadIdx.x&63, w=threadIdx.x>>6;
    if(lane==0){ sgp[w]=pg; sep[w]=pe; }
    __syncthreads();
    if(threadIdx.x==0){ s_bg=sgp[0]+sgp[1]+sgp[2]+sgp[3]; s_be=sep[0]+sep[1]+sep[2]+sep[3]; }
    __syncthreads();
  }
  int i = blockIdx.x*256 + threadIdx.x;
  int gt=0, eq=0;
  if(i<n){ unsigned o=ordf(score[i]); gt=(o>vthr); eq=(o==vthr); }
  unsigned long long bg=__ballot(gt), be=__ballot(eq);
  int lane=threadIdx.x&63, w=threadIdx.x>>6;
  unsigned long long mask = lane ? (~0ull >> (64-lane)) : 0ull;
  int pg = __popcll(bg & mask), pe = __popcll(be & mask);
  __shared__ int sg[4], se[4];
  if(lane==63){ sg[w]=pg+gt; se[w]=pe+eq; }
  __syncthreads();
  int wg=0,we=0;
  for(int j=0;j<w;j++){ wg+=sg[j]; we+=se[j]; }
  if(i<n){
    int gtp = s_bg + wg + pg;
    int eqp = s_be + we + pe;
    int sel = gt || (eq && (eqp < q));
    int ov = is_l0 ? i : ofc[i];
    if(sel){
      int pos = gtp + (eqp < q ? eqp : q);  // rank among selected, by original index
      oldidx[pos]=i;
      map[ov]=pos;
      ofn[pos]=ov;
    } else map[ov]=-1;
  }
}

// ---------------- epilogue ----------------

// per-feature max & mean over final nodes, input via indirection h[oldidx[r]]*score[oldidx[r]]
__global__ void pool_kernel(const float* __restrict__ h, const float* __restrict__ sc,
                            const int* __restrict__ oldidx, int n, float* __restrict__ xc){
  int f = blockIdx.x;
  float mx = -3.402823466e38f, sm=0.f;
  for(int r=threadIdx.x; r<n; r+=blockDim.x){
    int od = oldidx[r];
    float v = h[(size_t)od*256+f]*sc[od];
    mx = fmaxf(mx,v); sm += v;
  }
  __shared__ float smx[4], ssm[4];
  for(int o=32;o;o>>=1){ mx=fmaxf(mx,__shfl_down(mx,o,64)); sm+=__shfl_down(sm,o,64); }
  int lane=threadIdx.x&63, w=threadIdx.x>>6;
  if(lane==0){ smx[w]=mx; ssm[w]=sm; }
  __syncthreads();
  if(threadIdx.x==0){
    for(int j=1;j<4;j++){ mx=fmaxf(mx,smx[j]); sm+=ssm[j]; }
    xc[f]=mx; xc[256+f]=sm/(float)n;
  }
}

__global__ void fc_kernel(const float* __restrict__ xc, const float* __restrict__ fcw,
                          const float* __restrict__ fcb, const float* __restrict__ fc2w,
                          const float* __restrict__ fc2b, float* __restrict__ out){
  __shared__ float x[512];
  for(int i=threadIdx.x;i<512;i+=256) x[i]=xc[i];
  __syncthreads();
  int j=threadIdx.x;
  float a=fcb[j];
  for(int i=0;i<512;i++) a = fmaf(x[i], fcw[(size_t)j*512+i], a);
  a = a>0.f ? a : 0.f;
  float v = a*fc2w[j];
  for(int o=32;o;o>>=1) v += __shfl_down(v,o,64);
  __shared__ float sv[4];
  int lane=threadIdx.x&63, w=threadIdx.x>>6;
  if(lane==0) sv[w]=v;
  __syncthreads();
  if(threadIdx.x==0) out[0]=sv[0]+sv[1]+sv[2]+sv[3]+fc2b[0];
}

extern "C" void kernel_launch(void* const* d_in, const int* in_sizes, int n_in,
                              void* d_out, int out_size, void* d_ws, size_t ws_size,
                              hipStream_t stream) {
  const float* x   = (const float*)d_in[0];
  const int*   ei  = (const int*)d_in[1];
  const float* Wm[4] = {(const float*)d_in[2],(const float*)d_in[5],(const float*)d_in[8],(const float*)d_in[11]};
  const float* bv[4] = {(const float*)d_in[3],(const float*)d_in[6],(const float*)d_in[9],(const float*)d_in[12]};
  const float* pv[4] = {(const float*)d_in[4],(const float*)d_in[7],(const float*)d_in[10],(const float*)d_in[13]};
  const float* fcw  = (const float*)d_in[14];
  const float* fcb  = (const float*)d_in[15];
  const float* fc2w = (const float*)d_in[16];
  const float* fc2b = (const float*)d_in[17];

  char* base = (char*)d_ws; size_t off=0;
  auto alloc = [&](size_t bytes)->void*{
    void* p = base + off; off += (bytes + 511) & ~(size_t)511; return p;
  };
  int*   csr0   = (int*)  alloc((size_t)163842*CAP*4);
  int*   csr1   = (int*)  alloc((size_t)81921*CAP*4);
  int*   csr2   = (int*)  alloc((size_t)40961*CAP*4);
  int*   csr3   = (int*)  alloc((size_t)20481*CAP*4);
  float* score  = (float*)alloc((size_t)NV*4);
  int*   oldidx = (int*)  alloc((size_t)NV*4);
  int*   map    = (int*)  alloc((size_t)NV*4);   // orig-node -> current-layer idx (or -1)
  int*   ofA    = (int*)  alloc((size_t)NV*4);   // layer idx -> orig node, ping
  int*   ofB    = (int*)  alloc((size_t)NV*4);   // pong
  float* g      = (float*)alloc((size_t)2621568*4);
  float* hfull  = (float*)alloc((size_t)5243136*4);
  int*   blkGt  = (int*)  alloc(4096);
  int*   blkEq  = (int*)  alloc(4096);
  float* xc     = (float*)alloc(2048);
  // ---- zero-init region (ONE memset: per-layer histograms + degree arrays) ----
  size_t zero_start = off;
  int*   ghist  = (int*)  alloc((size_t)4*(2*65536+512)*4); // per layer: fh, fl, ch, cl
  int*   deg0   = (int*)  alloc((size_t)163842*4);
  int*   deg1   = (int*)  alloc((size_t)81921*4);
  int*   deg2   = (int*)  alloc((size_t)40961*4);
  int*   deg3   = (int*)  alloc((size_t)20481*4);
  size_t zero_len = off - zero_start;
  if (off > ws_size) return;

  hipMemsetAsync(base + zero_start, 0, zero_len, stream);

  const int ns[5]   = {163842, 81921, 40961, 20481, 10241};
  const int dims[5] = {4, 32, 64, 128, 256};
  const int foshf[4]= {5, 6, 7, 8};     // log2(Fo)
  const int qshf[4] = {0, 3, 4, 5};     // log2(Fi/4)
  int* degs[4] = {deg0, deg1, deg2, deg3};
  int* csrs[4] = {csr0, csr1, csr2, csr3};

  const float* hprev = x;   // unused for l==0 path
  for(int l=0;l<4;l++){
    int n=ns[l], k=ns[l+1], Fi=dims[l], Fo=dims[l+1];
    int nb = (n+255)/256;
    int* gh_hi = ghist + (size_t)l*(2*65536+512);
    int* gh_lo = gh_hi + 65536;
    int* ch    = gh_lo + 65536;
    int* cl    = ch + 256;
    const int* ofc = (l&1) ? ofA : ofB;   // written by previous layer's compact
    int*       ofn = (l&1) ? ofB : ofA;
    // ---- CSR (fixed capacity; l>0 built by previous csr_build_next) ----
    if(l==0) csr_fill0<<<NBE,256,0,stream>>>(ei, deg0, csr0);
    // ---- aggregation ----
    long long nq = (long long)n << qshf[l];
    unsigned ggrid = (unsigned)((nq+255)/256);
    if(l==0)
      csr_gather4<<<ggrid,256,0,stream>>>(x, degs[0], csrs[0], g, n, Fi, qshf[0]);
    else
      csr_gather4_ind<<<ggrid,256,0,stream>>>(hprev, score, oldidx, degs[l], csrs[l], g, n, Fi, qshf[l]);
    // ---- LDS + register tiled fused dense + score ----
    int BM = 8192 >> foshf[l];
    unsigned mgrid = (unsigned)((n + BM - 1) / BM);
    matmul_relu_score_t<<<mgrid,256,0,stream>>>(g, Wm[l], bv[l], pv[l], hfull, score,
                                                n, Fi, Fo, foshf[l], BM, qshf[l]);
    // ---- top-k selection (two-level 16-bit; thresholds derived in consumers) ----
    hist_hi<<<256,256,0,stream>>>(score, n, gh_hi, ch);
    hist_lo<<<256,256,0,stream>>>(score, n, k, ch, gh_hi, gh_lo, cl);
    sel_blockcount<<<nb,256,0,stream>>>(score, n, k, ch, gh_hi, cl, gh_lo, blkGt, blkEq);
    compact<<<nb,256,0,stream>>>(score, n, k, ch, gh_hi, cl, gh_lo, blkGt, blkEq,
                                 oldidx, map, ofc, ofn, (l==0)?1:0);
    // ---- next-layer CSR straight from original edges through composed map ----
    if(l<3) csr_build_next<<<NBE,256,0,stream>>>(ei, map, degs[l+1], csrs[l+1]);
    hprev = hfull;
  }

  pool_kernel<<<256,256,0,stream>>>(hfull, score, oldidx, ns[4], xc);
  fc_kernel<<<1,256,0,stream>>>(xc, fcw, fcb, fc2w, fc2b, (float*)d_out);
}

// Round 12
// 681.969 us; speedup vs baseline: 2.5857x; 2.5857x over previous
//
#include <hip/hip_runtime.h>
#include <math.h>

#define NV 163842
#define NE 983052
#define NBE 3841   // ceil(NE/256)
#define CAP 32     // fixed CSR row capacity (max in-degree; Poisson(6) tail ~1e-13)
#define CAPSH 5

// order-preserving float->uint transform (descending top-k: larger value -> larger key)
static __device__ __forceinline__ unsigned ordf(float f){
  unsigned u = __float_as_uint(f);
  return (u & 0x80000000u) ? ~u : (u | 0x80000000u);
}

// cooperative (256 threads): find bin (descending key order) where cumulative count
// crosses `rank`, from a 65536-bin fine histogram ONLY (coarse level derived by
// summing fine in-block — NO coarse atomic histogram; tanh key concentration would
// serialize coarse atomics, round-11 lesson). Returns bin; *rres = rank within bin.
__device__ int derive_level(const int* __restrict__ fine, int rank, int* rres){
  __shared__ int sh[256];
  __shared__ int s_c, s_r, s_b, s_q;
  int t = threadIdx.x;
  int cbase = (255-t)<<8;      // thread t owns descending chunk 255-t
  int v = 0;
  for(int u=0;u<256;u++) v += fine[cbase+u];
  sh[t]=v; __syncthreads();
  for(int o=1;o<256;o<<=1){ int tv=(t>=o)?sh[t-o]:0; __syncthreads(); sh[t]+=tv; __syncthreads(); }
  int excl = sh[t]-v;
  if(v>0 && excl<rank && rank<=excl+v){ s_c=255-t; s_r=rank-excl; }
  __syncthreads();
  int cc=s_c, rr=s_r;
  __syncthreads();
  v = fine[(cc<<8)+(255-t)];
  sh[t]=v; __syncthreads();
  for(int o=1;o<256;o<<=1){ int tv=(t>=o)?sh[t-o]:0; __syncthreads(); sh[t]+=tv; __syncthreads(); }
  excl = sh[t]-v;
  if(v>0 && excl<rr && rr<=excl+v){ s_b=(cc<<8)+(255-t); s_q=rr-excl; }
  __syncthreads();
  int bin=s_b; *rres=s_q;
  __syncthreads();
  return bin;
}

// ---------------- CSR build (fixed capacity; fill+degree in ONE scatter pass) ----------------

__global__ void csr_fill0(const int* __restrict__ ei, int* __restrict__ deg,
                          int* __restrict__ csr){
  int e = blockIdx.x*256 + threadIdx.x;
  if(e>=NE) return;
  int s = ei[e], d = ei[NE+e];
  int slot = atomicAdd(&deg[d], 1);
  if(slot < CAP) csr[((size_t)d<<CAPSH)+slot] = s;
}

// layer l<3: rebuild next-layer CSR straight from the ORIGINAL edge list through the
// orig-space survival map (composed across layers by compact)
__global__ void csr_build_next(const int* __restrict__ ei, const int* __restrict__ map,
                               int* __restrict__ deg_next, int* __restrict__ csr_next){
  int e = blockIdx.x*256 + threadIdx.x;
  if(e>=NE) return;
  int ns = map[ei[e]];
  if(ns<0) return;
  int nd = map[ei[NE+e]];
  if(nd<0) return;
  int slot = atomicAdd(&deg_next[nd], 1);
  if(slot < CAP) csr_next[((size_t)nd<<CAPSH)+slot] = ns;
}

// ---------------- aggregation (gather, float4, norms inline) ----------------

__global__ void csr_gather4(const float* __restrict__ h, const int* __restrict__ degi,
                            const int* __restrict__ csr, float* __restrict__ g,
                            int n, int Fi, int qshift){
  long long t = (long long)blockIdx.x*blockDim.x + threadIdx.x;
  int d = (int)(t >> qshift);
  if(d>=n) return;
  int q = ((int)t & ((1<<qshift)-1)) << 2;
  int deg = degi[d];
  int dc = deg < CAP ? deg : CAP;
  float di = rsqrtf((float)deg + 1.0f);
  const int* row = csr + ((size_t)d<<CAPSH);
  float4 hv = *(const float4*)(h + (size_t)d*Fi + q);
  float4 acc = make_float4(hv.x*di, hv.y*di, hv.z*di, hv.w*di);
  for(int j=0;j<dc;j++){
    int s = row[j];
    float ds = rsqrtf((float)degi[s] + 1.0f);
    float4 hs = *(const float4*)(h + (size_t)s*Fi + q);
    acc.x = fmaf(hs.x, ds, acc.x);
    acc.y = fmaf(hs.y, ds, acc.y);
    acc.z = fmaf(hs.z, ds, acc.z);
    acc.w = fmaf(hs.w, ds, acc.w);
  }
  *(float4*)(g + (size_t)d*Fi + q) = make_float4(acc.x*di, acc.y*di, acc.z*di, acc.w*di);
}

// layers 1-3: pooled input read via indirection hprev[oldidx[.]]*scprev[oldidx[.]]
__global__ void csr_gather4_ind(const float* __restrict__ hprev, const float* __restrict__ scprev,
                                const int* __restrict__ oldidx, const int* __restrict__ degi,
                                const int* __restrict__ csr, float* __restrict__ g,
                                int n, int Fi, int qshift){
  long long t = (long long)blockIdx.x*blockDim.x + threadIdx.x;
  int d = (int)(t >> qshift);
  if(d>=n) return;
  int q = ((int)t & ((1<<qshift)-1)) << 2;
  int deg = degi[d];
  int dc = deg < CAP ? deg : CAP;
  float di = rsqrtf((float)deg + 1.0f);
  int od = oldidx[d];
  float wd = scprev[od]*di;
  const int* row = csr + ((size_t)d<<CAPSH);
  float4 hv = *(const float4*)(hprev + (size_t)od*Fi + q);
  float4 acc = make_float4(hv.x*wd, hv.y*wd, hv.z*wd, hv.w*wd);
  for(int j=0;j<dc;j++){
    int s = row[j];
    int os = oldidx[s];
    float ws = scprev[os]*rsqrtf((float)degi[s] + 1.0f);
    float4 hs = *(const float4*)(hprev + (size_t)os*Fi + q);
    acc.x = fmaf(hs.x, ws, acc.x);
    acc.y = fmaf(hs.y, ws, acc.y);
    acc.z = fmaf(hs.z, ws, acc.z);
    acc.w = fmaf(hs.w, ws, acc.w);
  }
  *(float4*)(g + (size_t)d*Fi + q) = make_float4(acc.x*di, acc.y*di, acc.z*di, acc.w*di);
}

// ---------------- LDS-tiled, register-tiled fused dense (verified rounds 8-11) ----------------
__global__ void matmul_relu_score_t(const float* __restrict__ h, const float* __restrict__ W,
                                    const float* __restrict__ b, const float* __restrict__ p,
                                    float* __restrict__ out, float* __restrict__ score,
                                    int n, int Fi, int Fo, int foshf, int BM, int qsh){
  __shared__ float lh[4096];     // [BM][Fi], BM*Fi <= 4096
  __shared__ float pn_sh;
  int tid = threadIdx.x;
  if(tid < 64){
    float s=0.f;
    for(int f=tid; f<Fo; f+=64) s += p[f]*p[f];
    for(int o=32;o;o>>=1) s += __shfl_down(s,o,64);
    if(tid==0) pn_sh = rsqrtf(s);
  }
  int rb = blockIdx.x*BM;
  int fq = Fi>>2;
  int total_q = BM*fq;
  for(int idx=tid; idx<total_q; idx+=256){
    int row = idx>>qsh, q = idx & (fq-1);
    float4 v = make_float4(0.f,0.f,0.f,0.f);
    if(rb+row < n) v = *(const float4*)(h + (size_t)(rb+row)*Fi + q*4);
    *(float4*)(lh + (size_t)row*Fi + q*4) = v;
  }
  __syncthreads();
  int CG = Fo>>2;
  int colg = tid & (CG-1);
  int rowg = tid >> (foshf-2);
  int r0 = rowg<<3;
  int c0 = colg<<2;
  float acc[8][4];
  #pragma unroll
  for(int j=0;j<8;j++){ acc[j][0]=0.f; acc[j][1]=0.f; acc[j][2]=0.f; acc[j][3]=0.f; }
  for(int i=0;i<Fi;i+=4){
    const float* Wp = W + (size_t)i*Fo + c0;
    float4 w0 = *(const float4*)(Wp);
    float4 w1 = *(const float4*)(Wp + Fo);
    float4 w2 = *(const float4*)(Wp + 2*Fo);
    float4 w3 = *(const float4*)(Wp + 3*Fo);
    const float* lp = lh + (size_t)r0*Fi + i;
    #pragma unroll
    for(int j=0;j<8;j++){
      float4 hv = *(const float4*)(lp + (size_t)j*Fi);
      acc[j][0] = fmaf(hv.x,w0.x, fmaf(hv.y,w1.x, fmaf(hv.z,w2.x, fmaf(hv.w,w3.x, acc[j][0]))));
      acc[j][1] = fmaf(hv.x,w0.y, fmaf(hv.y,w1.y, fmaf(hv.z,w2.y, fmaf(hv.w,w3.y, acc[j][1]))));
      acc[j][2] = fmaf(hv.x,w0.z, fmaf(hv.y,w1.z, fmaf(hv.z,w2.z, fmaf(hv.w,w3.z, acc[j][2]))));
      acc[j][3] = fmaf(hv.x,w0.w, fmaf(hv.y,w1.w, fmaf(hv.z,w2.w, fmaf(hv.w,w3.w, acc[j][3]))));
    }
  }
  float4 bc = *(const float4*)(b + c0);
  float4 pc = *(const float4*)(p + c0);
  int width = CG;   // <= 64 always (Fo <= 256)
  #pragma unroll
  for(int j=0;j<8;j++){
    int row = rb + r0 + j;
    float v0 = fmaxf(acc[j][0]+bc.x, 0.f);
    float v1 = fmaxf(acc[j][1]+bc.y, 0.f);
    float v2 = fmaxf(acc[j][2]+bc.z, 0.f);
    float v3 = fmaxf(acc[j][3]+bc.w, 0.f);
    if(row < n) *(float4*)(out + (size_t)row*Fo + c0) = make_float4(v0,v1,v2,v3);
    float sc = v0*pc.x + v1*pc.y + v2*pc.z + v3*pc.w;
    for(int o=width>>1; o; o>>=1) sc += __shfl_down(sc, o, width);
    if(colg==0 && row<n) score[row] = tanhf(sc * pn_sh);
  }
}

// ---------------- grid-wide two-level 16-bit top-k select (fine histograms only) ----------------
__global__ void hist_hi(const float* __restrict__ score, int n, int* __restrict__ fine){
  int T = gridDim.x*blockDim.x;
  int lane = threadIdx.x&63;
  for(int base=0; base<n; base+=T){
    int i = base + blockIdx.x*blockDim.x + threadIdx.x;
    bool act = i<n;
    unsigned key = act ? (ordf(score[i])>>16) : 0u;
    unsigned long long eq = __ballot(act);
    #pragma unroll
    for(int bit=0;bit<16;bit++){
      unsigned long long bb = __ballot(act && ((key>>bit)&1u));
      eq &= ((key>>bit)&1u) ? bb : ~bb;
    }
    if(act){
      int lead = __ffsll(eq)-1;
      if(lane==lead) atomicAdd(&fine[key], __popcll(eq));
    }
  }
}

// derive hi-bin in-block from completed hi fine histogram, then histogram lo 16 bits
__global__ void hist_lo(const float* __restrict__ score, int n, int k,
                        const int* __restrict__ fh, int* __restrict__ fine){
  int r1;
  unsigned hi = (unsigned)derive_level(fh, k, &r1);
  int T = gridDim.x*blockDim.x;
  int lane = threadIdx.x&63;
  for(int base=0; base<n; base+=T){
    int i = base + blockIdx.x*blockDim.x + threadIdx.x;
    unsigned o = (i<n) ? ordf(score[i]) : 0u;
    bool act = (i<n) && ((o>>16)==hi);
    unsigned key = o & 0xFFFFu;
    unsigned long long eq = __ballot(act);
    #pragma unroll
    for(int bit=0;bit<16;bit++){
      unsigned long long bb = __ballot(act && ((key>>bit)&1u));
      eq &= ((key>>bit)&1u) ? bb : ~bb;
    }
    if(act){
      int lead = __ffsll(eq)-1;
      if(lane==lead) atomicAdd(&fine[key], __popcll(eq));
    }
  }
}

// ---------------- selection compaction (threshold derived in-block from fine hists) ----------------

__global__ void sel_blockcount(const float* __restrict__ score, int n, int k,
                               const int* __restrict__ fh, const int* __restrict__ fl,
                               int* __restrict__ blkGt, int* __restrict__ blkEq){
  int r1, q;
  int hi = derive_level(fh, k, &r1);
  int lo = derive_level(fl, r1, &q);
  unsigned vthr = ((unsigned)hi<<16)|(unsigned)lo;
  int i = blockIdx.x*256 + threadIdx.x;
  int gt=0, eq=0;
  if(i<n){ unsigned o=ordf(score[i]); gt = (o>vthr); eq = (o==vthr); }
  unsigned long long bg=__ballot(gt), be=__ballot(eq);
  __shared__ int sg[4], se[4];
  int lane=threadIdx.x&63, w=threadIdx.x>>6;
  if(lane==0){ sg[w]=__popcll(bg); se[w]=__popcll(be); }
  __syncthreads();
  if(threadIdx.x==0){
    int g=0,e=0;
    for(int j=0;j<4;j++){ g+=sg[j]; e+=se[j]; }
    blkGt[blockIdx.x]=g; blkEq[blockIdx.x]=e;
  }
}

// selects top-k set; writes oldidx (new->old) AND composes the orig-space survival map
__global__ void compact(const float* __restrict__ score, int n, int k,
                        const int* __restrict__ fh, const int* __restrict__ fl,
                        const int* __restrict__ blkGt, const int* __restrict__ blkEq,
                        int* __restrict__ oldidx, int* __restrict__ map,
                        const int* __restrict__ ofc, int* __restrict__ ofn, int is_l0){
  int r1, q;
  int hi = derive_level(fh, k, &r1);
  int lo = derive_level(fl, r1, &q);
  unsigned vthr = ((unsigned)hi<<16)|(unsigned)lo;
  __shared__ int s_bg, s_be;
  {
    int pg=0, pe=0;
    for(int j=threadIdx.x; j<(int)blockIdx.x; j+=256){ pg+=blkGt[j]; pe+=blkEq[j]; }
    for(int o=32;o;o>>=1){ pg+=__shfl_down(pg,o,64); pe+=__shfl_down(pe,o,64); }
    __shared__ int sgp[4], sep[4];
    int lane=threadIdx.x&63, w=threadIdx.x>>6;
    if(lane==0){ sgp[w]=pg; sep[w]=pe; }
    __syncthreads();
    if(threadIdx.x==0){ s_bg=sgp[0]+sgp[1]+sgp[2]+sgp[3]; s_be=sep[0]+sep[1]+sep[2]+sep[3]; }
    __syncthreads();
  }
  int i = blockIdx.x*256 + threadIdx.x;
  int gt=0, eq=0;
  if(i<n){ unsigned o=ordf(score[i]); gt=(o>vthr); eq=(o==vthr); }
  unsigned long long bg=__ballot(gt), be=__ballot(eq);
  int lane=threadIdx.x&63, w=threadIdx.x>>6;
  unsigned long long mask = lane ? (~0ull >> (64-lane)) : 0ull;
  int pg = __popcll(bg & mask), pe = __popcll(be & mask);
  __shared__ int sg[4], se[4];
  if(lane==63){ sg[w]=pg+gt; se[w]=pe+eq; }
  __syncthreads();
  int wg=0,we=0;
  for(int j=0;j<w;j++){ wg+=sg[j]; we+=se[j]; }
  if(i<n){
    int gtp = s_bg + wg + pg;
    int eqp = s_be + we + pe;
    int sel = gt || (eq && (eqp < q));
    int ov = is_l0 ? i : ofc[i];
    if(sel){
      int pos = gtp + (eqp < q ? eqp : q);  // rank among selected, by original index
      oldidx[pos]=i;
      map[ov]=pos;
      ofn[pos]=ov;
    } else map[ov]=-1;
  }
}

// ---------------- epilogue ----------------

__global__ void pool_kernel(const float* __restrict__ h, const float* __restrict__ sc,
                            const int* __restrict__ oldidx, int n, float* __restrict__ xc){
  int f = blockIdx.x;
  float mx = -3.402823466e38f, sm=0.f;
  for(int r=threadIdx.x; r<n; r+=blockDim.x){
    int od = oldidx[r];
    float v = h[(size_t)od*256+f]*sc[od];
    mx = fmaxf(mx,v); sm += v;
  }
  __shared__ float smx[4], ssm[4];
  for(int o=32;o;o>>=1){ mx=fmaxf(mx,__shfl_down(mx,o,64)); sm+=__shfl_down(sm,o,64); }
  int lane=threadIdx.x&63, w=threadIdx.x>>6;
  if(lane==0){ smx[w]=mx; ssm[w]=sm; }
  __syncthreads();
  if(threadIdx.x==0){
    for(int j=1;j<4;j++){ mx=fmaxf(mx,smx[j]); sm+=ssm[j]; }
    xc[f]=mx; xc[256+f]=sm/(float)n;
  }
}

__global__ void fc_kernel(const float* __restrict__ xc, const float* __restrict__ fcw,
                          const float* __restrict__ fcb, const float* __restrict__ fc2w,
                          const float* __restrict__ fc2b, float* __restrict__ out){
  __shared__ float x[512];
  for(int i=threadIdx.x;i<512;i+=256) x[i]=xc[i];
  __syncthreads();
  int j=threadIdx.x;
  float a=fcb[j];
  for(int i=0;i<512;i++) a = fmaf(x[i], fcw[(size_t)j*512+i], a);
  a = a>0.f ? a : 0.f;
  float v = a*fc2w[j];
  for(int o=32;o;o>>=1) v += __shfl_down(v,o,64);
  __shared__ float sv[4];
  int lane=threadIdx.x&63, w=threadIdx.x>>6;
  if(lane==0) sv[w]=v;
  __syncthreads();
  if(threadIdx.x==0) out[0]=sv[0]+sv[1]+sv[2]+sv[3]+fc2b[0];
}

extern "C" void kernel_launch(void* const* d_in, const int* in_sizes, int n_in,
                              void* d_out, int out_size, void* d_ws, size_t ws_size,
                              hipStream_t stream) {
  const float* x   = (const float*)d_in[0];
  const int*   ei  = (const int*)d_in[1];
  const float* Wm[4] = {(const float*)d_in[2],(const float*)d_in[5],(const float*)d_in[8],(const float*)d_in[11]};
  const float* bv[4] = {(const float*)d_in[3],(const float*)d_in[6],(const float*)d_in[9],(const float*)d_in[12]};
  const float* pv[4] = {(const float*)d_in[4],(const float*)d_in[7],(const float*)d_in[10],(const float*)d_in[13]};
  const float* fcw  = (const float*)d_in[14];
  const float* fcb  = (const float*)d_in[15];
  const float* fc2w = (const float*)d_in[16];
  const float* fc2b = (const float*)d_in[17];

  char* base = (char*)d_ws; size_t off=0;
  auto alloc = [&](size_t bytes)->void*{
    void* p = base + off; off += (bytes + 511) & ~(size_t)511; return p;
  };
  int*   csr0   = (int*)  alloc((size_t)163842*CAP*4);
  int*   csr1   = (int*)  alloc((size_t)81921*CAP*4);
  int*   csr2   = (int*)  alloc((size_t)40961*CAP*4);
  int*   csr3   = (int*)  alloc((size_t)20481*CAP*4);
  float* score  = (float*)alloc((size_t)NV*4);
  int*   oldidx = (int*)  alloc((size_t)NV*4);
  int*   map    = (int*)  alloc((size_t)NV*4);   // orig-node -> current-layer idx (or -1)
  int*   ofA    = (int*)  alloc((size_t)NV*4);   // layer idx -> orig node, ping
  int*   ofB    = (int*)  alloc((size_t)NV*4);   // pong
  float* g      = (float*)alloc((size_t)2621568*4);
  float* hfull  = (float*)alloc((size_t)5243136*4);
  int*   blkGt  = (int*)  alloc(4096);
  int*   blkEq  = (int*)  alloc(4096);
  float* xc     = (float*)alloc(2048);
  // ---- zero-init region (ONE memset: per-layer fine histograms + degree arrays) ----
  size_t zero_start = off;
  int*   ghist  = (int*)  alloc((size_t)4*2*65536*4); // per layer: fh, fl
  int*   deg0   = (int*)  alloc((size_t)163842*4);
  int*   deg1   = (int*)  alloc((size_t)81921*4);
  int*   deg2   = (int*)  alloc((size_t)40961*4);
  int*   deg3   = (int*)  alloc((size_t)20481*4);
  size_t zero_len = off - zero_start;
  if (off > ws_size) return;

  hipMemsetAsync(base + zero_start, 0, zero_len, stream);

  const int ns[5]   = {163842, 81921, 40961, 20481, 10241};
  const int dims[5] = {4, 32, 64, 128, 256};
  const int foshf[4]= {5, 6, 7, 8};     // log2(Fo)
  const int qshf[4] = {0, 3, 4, 5};     // log2(Fi/4)
  int* degs[4] = {deg0, deg1, deg2, deg3};
  int* csrs[4] = {csr0, csr1, csr2, csr3};

  const float* hprev = x;   // unused for l==0 path
  for(int l=0;l<4;l++){
    int n=ns[l], k=ns[l+1], Fi=dims[l], Fo=dims[l+1];
    int nb = (n+255)/256;
    int* fh = ghist + (size_t)l*2*65536;
    int* fl = fh + 65536;
    const int* ofc = (l&1) ? ofA : ofB;   // written by previous layer's compact
    int*       ofn = (l&1) ? ofB : ofA;
    // ---- CSR (fixed capacity; l>0 built by previous csr_build_next) ----
    if(l==0) csr_fill0<<<NBE,256,0,stream>>>(ei, deg0, csr0);
    // ---- aggregation ----
    long long nq = (long long)n << qshf[l];
    unsigned ggrid = (unsigned)((nq+255)/256);
    if(l==0)
      csr_gather4<<<ggrid,256,0,stream>>>(x, degs[0], csrs[0], g, n, Fi, qshf[0]);
    else
      csr_gather4_ind<<<ggrid,256,0,stream>>>(hprev, score, oldidx, degs[l], csrs[l], g, n, Fi, qshf[l]);
    // ---- LDS + register tiled fused dense + score ----
    int BM = 8192 >> foshf[l];
    unsigned mgrid = (unsigned)((n + BM - 1) / BM);
    matmul_relu_score_t<<<mgrid,256,0,stream>>>(g, Wm[l], bv[l], pv[l], hfull, score,
                                                n, Fi, Fo, foshf[l], BM, qshf[l]);
    // ---- top-k selection (two-level 16-bit; fine hists only, thresholds in consumers) ----
    hist_hi<<<256,256,0,stream>>>(score, n, fh);
    hist_lo<<<256,256,0,stream>>>(score, n, k, fh, fl);
    sel_blockcount<<<nb,256,0,stream>>>(score, n, k, fh, fl, blkGt, blkEq);
    compact<<<nb,256,0,stream>>>(score, n, k, fh, fl, blkGt, blkEq,
                                 oldidx, map, ofc, ofn, (l==0)?1:0);
    // ---- next-layer CSR straight from original edges through composed map ----
    if(l<3) csr_build_next<<<NBE,256,0,stream>>>(ei, map, degs[l+1], csrs[l+1]);
    hprev = hfull;
  }

  pool_kernel<<<256,256,0,stream>>>(hfull, score, oldidx, ns[4], xc);
  fc_kernel<<<1,256,0,stream>>>(xc, fcw, fcb, fc2w, fc2b, (float*)d_out);
}

// Round 13
// 635.250 us; speedup vs baseline: 2.7759x; 1.0735x over previous
//
#include <hip/hip_runtime.h>
#include <math.h>

#define NV 163842
#define NE 983052
#define NBE2 1921  // ceil(NE/2/256)
#define CAP 32     // fixed CSR row capacity (max in-degree; Poisson(6) tail ~1e-13)
#define CAPSH 5

// order-preserving float->uint transform (descending top-k: larger value -> larger key)
static __device__ __forceinline__ unsigned ordf(float f){
  unsigned u = __float_as_uint(f);
  return (u & 0x80000000u) ? ~u : (u | 0x80000000u);
}

// cooperative (256 threads): find bin (descending key order) where cumulative count
// crosses `rank` in a 65536-bin fine histogram (coarse level derived by in-block
// summation — NO coarse atomic histogram; round-11 lesson). *rres = rank within bin.
__device__ int derive_level(const int* __restrict__ fine, int rank, int* rres){
  __shared__ int sh[256];
  __shared__ int s_c, s_r, s_b, s_q;
  int t = threadIdx.x;
  int cbase = (255-t)<<8;
  int v = 0;
  for(int u=0;u<256;u++) v += fine[cbase+u];
  sh[t]=v; __syncthreads();
  for(int o=1;o<256;o<<=1){ int tv=(t>=o)?sh[t-o]:0; __syncthreads(); sh[t]+=tv; __syncthreads(); }
  int excl = sh[t]-v;
  if(v>0 && excl<rank && rank<=excl+v){ s_c=255-t; s_r=rank-excl; }
  __syncthreads();
  int cc=s_c, rr=s_r;
  __syncthreads();
  v = fine[(cc<<8)+(255-t)];
  sh[t]=v; __syncthreads();
  for(int o=1;o<256;o<<=1){ int tv=(t>=o)?sh[t-o]:0; __syncthreads(); sh[t]+=tv; __syncthreads(); }
  excl = sh[t]-v;
  if(v>0 && excl<rr && rr<=excl+v){ s_b=(cc<<8)+(255-t); s_q=rr-excl; }
  __syncthreads();
  int bin=s_b; *rres=s_q;
  __syncthreads();
  return bin;
}

// ---------------- CSR build (fixed capacity; 2 edges per thread, int2 loads) ----------------

__global__ void csr_fill0(const int* __restrict__ ei, int* __restrict__ deg,
                          int* __restrict__ csr){
  int e = (blockIdx.x*256 + threadIdx.x)*2;
  if(e>=NE) return;
  int2 ss = *(const int2*)(ei+e);
  int2 dd = *(const int2*)(ei+NE+e);
  int slot = atomicAdd(&deg[dd.x], 1);
  if(slot < CAP) csr[((size_t)dd.x<<CAPSH)+slot] = ss.x;
  slot = atomicAdd(&deg[dd.y], 1);
  if(slot < CAP) csr[((size_t)dd.y<<CAPSH)+slot] = ss.y;
}

// rebuild next-layer CSR straight from ORIGINAL edges through the composed survival map
__global__ void csr_build_next(const int* __restrict__ ei, const int* __restrict__ map,
                               int* __restrict__ deg_next, int* __restrict__ csr_next){
  int e = (blockIdx.x*256 + threadIdx.x)*2;
  if(e>=NE) return;
  int2 ss = *(const int2*)(ei+e);
  int2 dd = *(const int2*)(ei+NE+e);
  int ns0 = map[ss.x];
  if(ns0>=0){
    int nd0 = map[dd.x];
    if(nd0>=0){
      int slot = atomicAdd(&deg_next[nd0], 1);
      if(slot < CAP) csr_next[((size_t)nd0<<CAPSH)+slot] = ns0;
    }
  }
  int ns1 = map[ss.y];
  if(ns1>=0){
    int nd1 = map[dd.y];
    if(nd1>=0){
      int slot = atomicAdd(&deg_next[nd1], 1);
      if(slot < CAP) csr_next[((size_t)nd1<<CAPSH)+slot] = ns1;
    }
  }
}

// ---------------- aggregation (gather, float4, norms inline) ----------------

__global__ void csr_gather4(const float* __restrict__ h, const int* __restrict__ degi,
                            const int* __restrict__ csr, float* __restrict__ g,
                            int n, int Fi, int qshift){
  long long t = (long long)blockIdx.x*blockDim.x + threadIdx.x;
  int d = (int)(t >> qshift);
  if(d>=n) return;
  int q = ((int)t & ((1<<qshift)-1)) << 2;
  int deg = degi[d];
  int dc = deg < CAP ? deg : CAP;
  float di = rsqrtf((float)deg + 1.0f);
  const int* row = csr + ((size_t)d<<CAPSH);
  float4 hv = *(const float4*)(h + (size_t)d*Fi + q);
  float4 acc = make_float4(hv.x*di, hv.y*di, hv.z*di, hv.w*di);
  for(int j=0;j<dc;j++){
    int s = row[j];
    float ds = rsqrtf((float)degi[s] + 1.0f);
    float4 hs = *(const float4*)(h + (size_t)s*Fi + q);
    acc.x = fmaf(hs.x, ds, acc.x);
    acc.y = fmaf(hs.y, ds, acc.y);
    acc.z = fmaf(hs.z, ds, acc.z);
    acc.w = fmaf(hs.w, ds, acc.w);
  }
  *(float4*)(g + (size_t)d*Fi + q) = make_float4(acc.x*di, acc.y*di, acc.z*di, acc.w*di);
}

// layers 1-3: pooled input read via indirection hprev[oldidx[.]]*scprev[oldidx[.]]
__global__ void csr_gather4_ind(const float* __restrict__ hprev, const float* __restrict__ scprev,
                                const int* __restrict__ oldidx, const int* __restrict__ degi,
                                const int* __restrict__ csr, float* __restrict__ g,
                                int n, int Fi, int qshift){
  long long t = (long long)blockIdx.x*blockDim.x + threadIdx.x;
  int d = (int)(t >> qshift);
  if(d>=n) return;
  int q = ((int)t & ((1<<qshift)-1)) << 2;
  int deg = degi[d];
  int dc = deg < CAP ? deg : CAP;
  float di = rsqrtf((float)deg + 1.0f);
  int od = oldidx[d];
  float wd = scprev[od]*di;
  const int* row = csr + ((size_t)d<<CAPSH);
  float4 hv = *(const float4*)(hprev + (size_t)od*Fi + q);
  float4 acc = make_float4(hv.x*wd, hv.y*wd, hv.z*wd, hv.w*wd);
  for(int j=0;j<dc;j++){
    int s = row[j];
    int os = oldidx[s];
    float ws = scprev[os]*rsqrtf((float)degi[s] + 1.0f);
    float4 hs = *(const float4*)(hprev + (size_t)os*Fi + q);
    acc.x = fmaf(hs.x, ws, acc.x);
    acc.y = fmaf(hs.y, ws, acc.y);
    acc.z = fmaf(hs.z, ws, acc.z);
    acc.w = fmaf(hs.w, ws, acc.w);
  }
  *(float4*)(g + (size_t)d*Fi + q) = make_float4(acc.x*di, acc.y*di, acc.z*di, acc.w*di);
}

// ---------------- LDS-tiled, register-tiled fused dense + score + hi-16 histogram ----------------
// hfull = relu(g@W+b); score = tanh(hfull.p/||p||); fh[hi16(score)] += 1 (wave-aggregated)
__global__ void matmul_relu_score_t(const float* __restrict__ h, const float* __restrict__ W,
                                    const float* __restrict__ b, const float* __restrict__ p,
                                    float* __restrict__ out, float* __restrict__ score,
                                    int* __restrict__ fh,
                                    int n, int Fi, int Fo, int foshf, int BM, int qsh){
  __shared__ float lh[4096];     // [BM][Fi], BM*Fi <= 4096
  __shared__ float pn_sh;
  int tid = threadIdx.x;
  if(tid < 64){
    float s=0.f;
    for(int f=tid; f<Fo; f+=64) s += p[f]*p[f];
    for(int o=32;o;o>>=1) s += __shfl_down(s,o,64);
    if(tid==0) pn_sh = rsqrtf(s);
  }
  int rb = blockIdx.x*BM;
  int fq = Fi>>2;
  int total_q = BM*fq;
  for(int idx=tid; idx<total_q; idx+=256){
    int row = idx>>qsh, q = idx & (fq-1);
    float4 v = make_float4(0.f,0.f,0.f,0.f);
    if(rb+row < n) v = *(const float4*)(h + (size_t)(rb+row)*Fi + q*4);
    *(float4*)(lh + (size_t)row*Fi + q*4) = v;
  }
  __syncthreads();
  int CG = Fo>>2;
  int colg = tid & (CG-1);
  int rowg = tid >> (foshf-2);
  int r0 = rowg<<3;
  int c0 = colg<<2;
  float acc[8][4];
  #pragma unroll
  for(int j=0;j<8;j++){ acc[j][0]=0.f; acc[j][1]=0.f; acc[j][2]=0.f; acc[j][3]=0.f; }
  for(int i=0;i<Fi;i+=4){
    const float* Wp = W + (size_t)i*Fo + c0;
    float4 w0 = *(const float4*)(Wp);
    float4 w1 = *(const float4*)(Wp + Fo);
    float4 w2 = *(const float4*)(Wp + 2*Fo);
    float4 w3 = *(const float4*)(Wp + 3*Fo);
    const float* lp = lh + (size_t)r0*Fi + i;
    #pragma unroll
    for(int j=0;j<8;j++){
      float4 hv = *(const float4*)(lp + (size_t)j*Fi);
      acc[j][0] = fmaf(hv.x,w0.x, fmaf(hv.y,w1.x, fmaf(hv.z,w2.x, fmaf(hv.w,w3.x, acc[j][0]))));
      acc[j][1] = fmaf(hv.x,w0.y, fmaf(hv.y,w1.y, fmaf(hv.z,w2.y, fmaf(hv.w,w3.y, acc[j][1]))));
      acc[j][2] = fmaf(hv.x,w0.z, fmaf(hv.y,w1.z, fmaf(hv.z,w2.z, fmaf(hv.w,w3.z, acc[j][2]))));
      acc[j][3] = fmaf(hv.x,w0.w, fmaf(hv.y,w1.w, fmaf(hv.z,w2.w, fmaf(hv.w,w3.w, acc[j][3]))));
    }
  }
  float4 bc = *(const float4*)(b + c0);
  float4 pc = *(const float4*)(p + c0);
  int width = CG;   // <= 64 always (Fo <= 256)
  int lane = tid & 63;
  #pragma unroll
  for(int j=0;j<8;j++){
    int row = rb + r0 + j;
    float v0 = fmaxf(acc[j][0]+bc.x, 0.f);
    float v1 = fmaxf(acc[j][1]+bc.y, 0.f);
    float v2 = fmaxf(acc[j][2]+bc.z, 0.f);
    float v3 = fmaxf(acc[j][3]+bc.w, 0.f);
    if(row < n) *(float4*)(out + (size_t)row*Fo + c0) = make_float4(v0,v1,v2,v3);
    float sc = v0*pc.x + v1*pc.y + v2*pc.z + v3*pc.w;
    for(int o=width>>1; o; o>>=1) sc += __shfl_down(sc, o, width);
    bool act = (colg==0 && row<n);
    float scv = 0.f;
    unsigned key = 0u;
    if(act){
      scv = tanhf(sc * pn_sh);
      score[row] = scv;
      key = ordf(scv)>>16;
    }
    // wave-aggregated fine-histogram update
    unsigned long long eqm = __ballot(act);
    #pragma unroll
    for(int bit=0;bit<16;bit++){
      unsigned long long bb = __ballot(act && ((key>>bit)&1u));
      eqm &= ((key>>bit)&1u) ? bb : ~bb;
    }
    if(act){
      int lead = __ffsll(eqm)-1;
      if(lane==lead) atomicAdd(&fh[key], __popcll(eqm));
    }
  }
}

// ---------------- top-k select: lo-16 histogram + single-block threshold find ----------------

// derive hi-bin in-block from completed hi fine histogram, then histogram lo 16 bits
__global__ void hist_lo(const float* __restrict__ score, int n, int k,
                        const int* __restrict__ fh, int* __restrict__ fine){
  int r1;
  unsigned hi = (unsigned)derive_level(fh, k, &r1);
  int T = gridDim.x*blockDim.x;
  int lane = threadIdx.x&63;
  for(int base=0; base<n; base+=T){
    int i = base + blockIdx.x*blockDim.x + threadIdx.x;
    unsigned o = (i<n) ? ordf(score[i]) : 0u;
    bool act = (i<n) && ((o>>16)==hi);
    unsigned key = o & 0xFFFFu;
    unsigned long long eq = __ballot(act);
    #pragma unroll
    for(int bit=0;bit<16;bit++){
      unsigned long long bb = __ballot(act && ((key>>bit)&1u));
      eq &= ((key>>bit)&1u) ? bb : ~bb;
    }
    if(act){
      int lead = __ffsll(eq)-1;
      if(lane==lead) atomicAdd(&fine[key], __popcll(eq));
    }
  }
}

// single block: (hi, rank) from fh, then exact 32-bit threshold + tie quota from fl
__global__ void find_thr(const int* __restrict__ fh, const int* __restrict__ fl,
                         int k, unsigned* __restrict__ out_thr, int* __restrict__ out_q){
  int r1, q;
  int hi = derive_level(fh, k, &r1);
  int lo = derive_level(fl, r1, &q);
  if(threadIdx.x==0){
    out_thr[0] = ((unsigned)hi<<16)|(unsigned)lo;
    out_q[0]   = q;
  }
}

// ---------------- selection compaction ----------------

__global__ void sel_blockcount(const float* __restrict__ score, int n,
                               const unsigned* __restrict__ thr,
                               int* __restrict__ blkGt, int* __restrict__ blkEq){
  int i = blockIdx.x*256 + threadIdx.x;
  unsigned vthr = thr[0];
  int gt=0, eq=0;
  if(i<n){ unsigned o=ordf(score[i]); gt = (o>vthr); eq = (o==vthr); }
  unsigned long long bg=__ballot(gt), be=__ballot(eq);
  __shared__ int sg[4], se[4];
  int lane=threadIdx.x&63, w=threadIdx.x>>6;
  if(lane==0){ sg[w]=__popcll(bg); se[w]=__popcll(be); }
  __syncthreads();
  if(threadIdx.x==0){
    int g=0,e=0;
    for(int j=0;j<4;j++){ g+=sg[j]; e+=se[j]; }
    blkGt[blockIdx.x]=g; blkEq[blockIdx.x]=e;
  }
}

// selects top-k; writes oldidx (new->old) AND composes the orig-space survival map;
// block prefix computed in-block from raw per-block counts (kernel-boundary safe)
__global__ void compact(const float* __restrict__ score, int n,
                        const unsigned* __restrict__ thr, const int* __restrict__ qp,
                        const int* __restrict__ blkGt, const int* __restrict__ blkEq,
                        int* __restrict__ oldidx, int* __restrict__ map,
                        const int* __restrict__ ofc, int* __restrict__ ofn, int is_l0){
  __shared__ int s_bg, s_be;
  {
    int pg=0, pe=0;
    for(int j=threadIdx.x; j<(int)blockIdx.x; j+=256){ pg+=blkGt[j]; pe+=blkEq[j]; }
    for(int o=32;o;o>>=1){ pg+=__shfl_down(pg,o,64); pe+=__shfl_down(pe,o,64); }
    __shared__ int sgp[4], sep[4];
    int lane=threadIdx.x&63, w=threadIdx.x>>6;
    if(lane==0){ sgp[w]=pg; sep[w]=pe; }
    __syncthreads();
    if(threadIdx.x==0){ s_bg=sgp[0]+sgp[1]+sgp[2]+sgp[3]; s_be=sep[0]+sep[1]+sep[2]+sep[3]; }
    __syncthreads();
  }
  int i = blockIdx.x*256 + threadIdx.x;
  unsigned vthr = thr[0];
  int q = qp[0];
  int gt=0, eq=0;
  if(i<n){ unsigned o=ordf(score[i]); gt=(o>vthr); eq=(o==vthr); }
  unsigned long long bg=__ballot(gt), be=__ballot(eq);
  int lane=threadIdx.x&63, w=threadIdx.x>>6;
  unsigned long long mask = lane ? (~0ull >> (64-lane)) : 0ull;
  int pg = __popcll(bg & mask), pe = __popcll(be & mask);
  __shared__ int sg[4], se[4];
  if(lane==63){ sg[w]=pg+gt; se[w]=pe+eq; }
  __syncthreads();
  int wg=0,we=0;
  for(int j=0;j<w;j++){ wg+=sg[j]; we+=se[j]; }
  if(i<n){
    int gtp = s_bg + wg + pg;
    int eqp = s_be + we + pe;
    int sel = gt || (eq && (eqp < q));
    int ov = is_l0 ? i : ofc[i];
    if(sel){
      int pos = gtp + (eqp < q ? eqp : q);  // rank among selected, by original index
      oldidx[pos]=i;
      map[ov]=pos;
      ofn[pos]=ov;
    } else map[ov]=-1;
  }
}

// ---------------- epilogue ----------------

__global__ void pool_kernel(const float* __restrict__ h, const float* __restrict__ sc,
                            const int* __restrict__ oldidx, int n, float* __restrict__ xc){
  int f = blockIdx.x;
  float mx = -3.402823466e38f, sm=0.f;
  for(int r=threadIdx.x; r<n; r+=blockDim.x){
    int od = oldidx[r];
    float v = h[(size_t)od*256+f]*sc[od];
    mx = fmaxf(mx,v); sm += v;
  }
  __shared__ float smx[4], ssm[4];
  for(int o=32;o;o>>=1){ mx=fmaxf(mx,__shfl_down(mx,o,64)); sm+=__shfl_down(sm,o,64); }
  int lane=threadIdx.x&63, w=threadIdx.x>>6;
  if(lane==0){ smx[w]=mx; ssm[w]=sm; }
  __syncthreads();
  if(threadIdx.x==0){
    for(int j=1;j<4;j++){ mx=fmaxf(mx,smx[j]); sm+=ssm[j]; }
    xc[f]=mx; xc[256+f]=sm/(float)n;
  }
}

__global__ void fc_kernel(const float* __restrict__ xc, const float* __restrict__ fcw,
                          const float* __restrict__ fcb, const float* __restrict__ fc2w,
                          const float* __restrict__ fc2b, float* __restrict__ out){
  __shared__ float x[512];
  for(int i=threadIdx.x;i<512;i+=256) x[i]=xc[i];
  __syncthreads();
  int j=threadIdx.x;
  float a=fcb[j];
  for(int i=0;i<512;i++) a = fmaf(x[i], fcw[(size_t)j*512+i], a);
  a = a>0.f ? a : 0.f;
  float v = a*fc2w[j];
  for(int o=32;o;o>>=1) v += __shfl_down(v,o,64);
  __shared__ float sv[4];
  int lane=threadIdx.x&63, w=threadIdx.x>>6;
  if(lane==0) sv[w]=v;
  __syncthreads();
  if(threadIdx.x==0) out[0]=sv[0]+sv[1]+sv[2]+sv[3]+fc2b[0];
}

extern "C" void kernel_launch(void* const* d_in, const int* in_sizes, int n_in,
                              void* d_out, int out_size, void* d_ws, size_t ws_size,
                              hipStream_t stream) {
  const float* x   = (const float*)d_in[0];
  const int*   ei  = (const int*)d_in[1];
  const float* Wm[4] = {(const float*)d_in[2],(const float*)d_in[5],(const float*)d_in[8],(const float*)d_in[11]};
  const float* bv[4] = {(const float*)d_in[3],(const float*)d_in[6],(const float*)d_in[9],(const float*)d_in[12]};
  const float* pv[4] = {(const float*)d_in[4],(const float*)d_in[7],(const float*)d_in[10],(const float*)d_in[13]};
  const float* fcw  = (const float*)d_in[14];
  const float* fcb  = (const float*)d_in[15];
  const float* fc2w = (const float*)d_in[16];
  const float* fc2b = (const float*)d_in[17];

  char* base = (char*)d_ws; size_t off=0;
  auto alloc = [&](size_t bytes)->void*{
    void* p = base + off; off += (bytes + 511) & ~(size_t)511; return p;
  };
  int*   csr0   = (int*)  alloc((size_t)163842*CAP*4);
  int*   csr1   = (int*)  alloc((size_t)81921*CAP*4);
  int*   csr2   = (int*)  alloc((size_t)40961*CAP*4);
  int*   csr3   = (int*)  alloc((size_t)20481*CAP*4);
  float* score  = (float*)alloc((size_t)NV*4);
  int*   oldidx = (int*)  alloc((size_t)NV*4);
  int*   map    = (int*)  alloc((size_t)NV*4);   // orig-node -> current-layer idx (or -1)
  int*   ofA    = (int*)  alloc((size_t)NV*4);   // layer idx -> orig node, ping
  int*   ofB    = (int*)  alloc((size_t)NV*4);   // pong
  float* g      = (float*)alloc((size_t)2621568*4);
  float* hfull  = (float*)alloc((size_t)5243136*4);
  int*   blkGt  = (int*)  alloc(4096);
  int*   blkEq  = (int*)  alloc(4096);
  unsigned* thr = (unsigned*)alloc(64);
  int*   qv     = (int*)  alloc(64);
  float* xc     = (float*)alloc(2048);
  // ---- zero-init region (ONE memset: per-layer fine histograms + degree arrays) ----
  size_t zero_start = off;
  int*   ghist  = (int*)  alloc((size_t)4*2*65536*4); // per layer: fh, fl
  int*   deg0   = (int*)  alloc((size_t)163842*4);
  int*   deg1   = (int*)  alloc((size_t)81921*4);
  int*   deg2   = (int*)  alloc((size_t)40961*4);
  int*   deg3   = (int*)  alloc((size_t)20481*4);
  size_t zero_len = off - zero_start;
  if (off > ws_size) return;

  hipMemsetAsync(base + zero_start, 0, zero_len, stream);

  const int ns[5]   = {163842, 81921, 40961, 20481, 10241};
  const int dims[5] = {4, 32, 64, 128, 256};
  const int foshf[4]= {5, 6, 7, 8};     // log2(Fo)
  const int qshf[4] = {0, 3, 4, 5};     // log2(Fi/4)
  int* degs[4] = {deg0, deg1, deg2, deg3};
  int* csrs[4] = {csr0, csr1, csr2, csr3};

  const float* hprev = x;   // unused for l==0 path
  for(int l=0;l<4;l++){
    int n=ns[l], k=ns[l+1], Fi=dims[l], Fo=dims[l+1];
    int nb = (n+255)/256;
    int* fh = ghist + (size_t)l*2*65536;
    int* fl = fh + 65536;
    const int* ofc = (l&1) ? ofA : ofB;   // written by previous layer's compact
    int*       ofn = (l&1) ? ofB : ofA;
    // ---- CSR (fixed capacity; l>0 built by previous csr_build_next) ----
    if(l==0) csr_fill0<<<NBE2,256,0,stream>>>(ei, deg0, csr0);
    // ---- aggregation ----
    long long nq = (long long)n << qshf[l];
    unsigned ggrid = (unsigned)((nq+255)/256);
    if(l==0)
      csr_gather4<<<ggrid,256,0,stream>>>(x, degs[0], csrs[0], g, n, Fi, qshf[0]);
    else
      csr_gather4_ind<<<ggrid,256,0,stream>>>(hprev, score, oldidx, degs[l], csrs[l], g, n, Fi, qshf[l]);
    // ---- LDS + register tiled fused dense + score + hi-16 histogram ----
    int BM = 8192 >> foshf[l];
    unsigned mgrid = (unsigned)((n + BM - 1) / BM);
    matmul_relu_score_t<<<mgrid,256,0,stream>>>(g, Wm[l], bv[l], pv[l], hfull, score, fh,
                                                n, Fi, Fo, foshf[l], BM, qshf[l]);
    // ---- top-k selection ----
    hist_lo<<<256,256,0,stream>>>(score, n, k, fh, fl);
    find_thr<<<1,256,0,stream>>>(fh, fl, k, thr, qv);
    sel_blockcount<<<nb,256,0,stream>>>(score, n, thr, blkGt, blkEq);
    compact<<<nb,256,0,stream>>>(score, n, thr, qv, blkGt, blkEq,
                                 oldidx, map, ofc, ofn, (l==0)?1:0);
    // ---- next-layer CSR straight from original edges through composed map ----
    if(l<3) csr_build_next<<<NBE2,256,0,stream>>>(ei, map, degs[l+1], csrs[l+1]);
    hprev = hfull;
  }

  pool_kernel<<<256,256,0,stream>>>(hfull, score, oldidx, ns[4], xc);
  fc_kernel<<<1,256,0,stream>>>(xc, fcw, fcb, fc2w, fc2b, (float*)d_out);
}

// Round 14
// 548.133 us; speedup vs baseline: 3.2170x; 1.1589x over previous
//
#include <hip/hip_runtime.h>
#include <math.h>

#define NV 163842
#define NE 983052
#define NBE2 1921  // ceil(NE/2/256)
#define CAP 32     // fixed CSR row capacity (max in-degree; Poisson(6) tail ~1e-13)
#define CAPSH 5

// order-preserving float->uint transform (descending top-k: larger value -> larger key)
static __device__ __forceinline__ unsigned ordf(float f){
  unsigned u = __float_as_uint(f);
  return (u & 0x80000000u) ? ~u : (u | 0x80000000u);
}

// cooperative (256 threads): find bin (descending key order) where cumulative count
// crosses `rank` in a 65536-bin fine histogram (coarse level derived by in-block
// summation — NO coarse atomic histogram; round-11 lesson). *rres = rank within bin.
__device__ int derive_level(const int* __restrict__ fine, int rank, int* rres){
  __shared__ int sh[256];
  __shared__ int s_c, s_r, s_b, s_q;
  int t = threadIdx.x;
  int cbase = (255-t)<<8;
  int v = 0;
  for(int u=0;u<256;u++) v += fine[cbase+u];
  sh[t]=v; __syncthreads();
  for(int o=1;o<256;o<<=1){ int tv=(t>=o)?sh[t-o]:0; __syncthreads(); sh[t]+=tv; __syncthreads(); }
  int excl = sh[t]-v;
  if(v>0 && excl<rank && rank<=excl+v){ s_c=255-t; s_r=rank-excl; }
  __syncthreads();
  int cc=s_c, rr=s_r;
  __syncthreads();
  v = fine[(cc<<8)+(255-t)];
  sh[t]=v; __syncthreads();
  for(int o=1;o<256;o<<=1){ int tv=(t>=o)?sh[t-o]:0; __syncthreads(); sh[t]+=tv; __syncthreads(); }
  excl = sh[t]-v;
  if(v>0 && excl<rr && rr<=excl+v){ s_b=(cc<<8)+(255-t); s_q=rr-excl; }
  __syncthreads();
  int bin=s_b; *rres=s_q;
  __syncthreads();
  return bin;
}

// ---------------- CSR build (fixed capacity; 2 edges per thread, int2 loads) ----------------

__global__ void csr_fill0(const int* __restrict__ ei, int* __restrict__ deg,
                          int* __restrict__ csr){
  int e = (blockIdx.x*256 + threadIdx.x)*2;
  if(e>=NE) return;
  int2 ss = *(const int2*)(ei+e);
  int2 dd = *(const int2*)(ei+NE+e);
  int slot = atomicAdd(&deg[dd.x], 1);
  if(slot < CAP) csr[((size_t)dd.x<<CAPSH)+slot] = ss.x;
  slot = atomicAdd(&deg[dd.y], 1);
  if(slot < CAP) csr[((size_t)dd.y<<CAPSH)+slot] = ss.y;
}

// rebuild next-layer CSR straight from ORIGINAL edges through the composed survival map
__global__ void csr_build_next(const int* __restrict__ ei, const int* __restrict__ map,
                               int* __restrict__ deg_next, int* __restrict__ csr_next){
  int e = (blockIdx.x*256 + threadIdx.x)*2;
  if(e>=NE) return;
  int2 ss = *(const int2*)(ei+e);
  int2 dd = *(const int2*)(ei+NE+e);
  int ns0 = map[ss.x];
  if(ns0>=0){
    int nd0 = map[dd.x];
    if(nd0>=0){
      int slot = atomicAdd(&deg_next[nd0], 1);
      if(slot < CAP) csr_next[((size_t)nd0<<CAPSH)+slot] = ns0;
    }
  }
  int ns1 = map[ss.y];
  if(ns1>=0){
    int nd1 = map[dd.y];
    if(nd1>=0){
      int slot = atomicAdd(&deg_next[nd1], 1);
      if(slot < CAP) csr_next[((size_t)nd1<<CAPSH)+slot] = ns1;
    }
  }
}

// ---------------- aggregation (gather, float4, norms inline) ----------------

__global__ void csr_gather4(const float* __restrict__ h, const int* __restrict__ degi,
                            const int* __restrict__ csr, float* __restrict__ g,
                            int n, int Fi, int qshift){
  long long t = (long long)blockIdx.x*blockDim.x + threadIdx.x;
  int d = (int)(t >> qshift);
  if(d>=n) return;
  int q = ((int)t & ((1<<qshift)-1)) << 2;
  int deg = degi[d];
  int dc = deg < CAP ? deg : CAP;
  float di = rsqrtf((float)deg + 1.0f);
  const int* row = csr + ((size_t)d<<CAPSH);
  float4 hv = *(const float4*)(h + (size_t)d*Fi + q);
  float4 acc = make_float4(hv.x*di, hv.y*di, hv.z*di, hv.w*di);
  for(int j=0;j<dc;j++){
    int s = row[j];
    float ds = rsqrtf((float)degi[s] + 1.0f);
    float4 hs = *(const float4*)(h + (size_t)s*Fi + q);
    acc.x = fmaf(hs.x, ds, acc.x);
    acc.y = fmaf(hs.y, ds, acc.y);
    acc.z = fmaf(hs.z, ds, acc.z);
    acc.w = fmaf(hs.w, ds, acc.w);
  }
  *(float4*)(g + (size_t)d*Fi + q) = make_float4(acc.x*di, acc.y*di, acc.z*di, acc.w*di);
}

// layers 1-3: pooled input read via indirection hprev[oldidx[.]]*scprev[oldidx[.]]
__global__ void csr_gather4_ind(const float* __restrict__ hprev, const float* __restrict__ scprev,
                                const int* __restrict__ oldidx, const int* __restrict__ degi,
                                const int* __restrict__ csr, float* __restrict__ g,
                                int n, int Fi, int qshift){
  long long t = (long long)blockIdx.x*blockDim.x + threadIdx.x;
  int d = (int)(t >> qshift);
  if(d>=n) return;
  int q = ((int)t & ((1<<qshift)-1)) << 2;
  int deg = degi[d];
  int dc = deg < CAP ? deg : CAP;
  float di = rsqrtf((float)deg + 1.0f);
  int od = oldidx[d];
  float wd = scprev[od]*di;
  const int* row = csr + ((size_t)d<<CAPSH);
  float4 hv = *(const float4*)(hprev + (size_t)od*Fi + q);
  float4 acc = make_float4(hv.x*wd, hv.y*wd, hv.z*wd, hv.w*wd);
  for(int j=0;j<dc;j++){
    int s = row[j];
    int os = oldidx[s];
    float ws = scprev[os]*rsqrtf((float)degi[s] + 1.0f);
    float4 hs = *(const float4*)(hprev + (size_t)os*Fi + q);
    acc.x = fmaf(hs.x, ws, acc.x);
    acc.y = fmaf(hs.y, ws, acc.y);
    acc.z = fmaf(hs.z, ws, acc.z);
    acc.w = fmaf(hs.w, ws, acc.w);
  }
  *(float4*)(g + (size_t)d*Fi + q) = make_float4(acc.x*di, acc.y*di, acc.z*di, acc.w*di);
}

// ---------------- LDS-tiled, register-tiled fused dense (clean epilogue, rounds 8-11) ----------------
__global__ void matmul_relu_score_t(const float* __restrict__ h, const float* __restrict__ W,
                                    const float* __restrict__ b, const float* __restrict__ p,
                                    float* __restrict__ out, float* __restrict__ score,
                                    int n, int Fi, int Fo, int foshf, int BM, int qsh){
  __shared__ float lh[4096];     // [BM][Fi], BM*Fi <= 4096
  __shared__ float pn_sh;
  int tid = threadIdx.x;
  if(tid < 64){
    float s=0.f;
    for(int f=tid; f<Fo; f+=64) s += p[f]*p[f];
    for(int o=32;o;o>>=1) s += __shfl_down(s,o,64);
    if(tid==0) pn_sh = rsqrtf(s);
  }
  int rb = blockIdx.x*BM;
  int fq = Fi>>2;
  int total_q = BM*fq;
  for(int idx=tid; idx<total_q; idx+=256){
    int row = idx>>qsh, q = idx & (fq-1);
    float4 v = make_float4(0.f,0.f,0.f,0.f);
    if(rb+row < n) v = *(const float4*)(h + (size_t)(rb+row)*Fi + q*4);
    *(float4*)(lh + (size_t)row*Fi + q*4) = v;
  }
  __syncthreads();
  int CG = Fo>>2;
  int colg = tid & (CG-1);
  int rowg = tid >> (foshf-2);
  int r0 = rowg<<3;
  int c0 = colg<<2;
  float acc[8][4];
  #pragma unroll
  for(int j=0;j<8;j++){ acc[j][0]=0.f; acc[j][1]=0.f; acc[j][2]=0.f; acc[j][3]=0.f; }
  for(int i=0;i<Fi;i+=4){
    const float* Wp = W + (size_t)i*Fo + c0;
    float4 w0 = *(const float4*)(Wp);
    float4 w1 = *(const float4*)(Wp + Fo);
    float4 w2 = *(const float4*)(Wp + 2*Fo);
    float4 w3 = *(const float4*)(Wp + 3*Fo);
    const float* lp = lh + (size_t)r0*Fi + i;
    #pragma unroll
    for(int j=0;j<8;j++){
      float4 hv = *(const float4*)(lp + (size_t)j*Fi);
      acc[j][0] = fmaf(hv.x,w0.x, fmaf(hv.y,w1.x, fmaf(hv.z,w2.x, fmaf(hv.w,w3.x, acc[j][0]))));
      acc[j][1] = fmaf(hv.x,w0.y, fmaf(hv.y,w1.y, fmaf(hv.z,w2.y, fmaf(hv.w,w3.y, acc[j][1]))));
      acc[j][2] = fmaf(hv.x,w0.z, fmaf(hv.y,w1.z, fmaf(hv.z,w2.z, fmaf(hv.w,w3.z, acc[j][2]))));
      acc[j][3] = fmaf(hv.x,w0.w, fmaf(hv.y,w1.w, fmaf(hv.z,w2.w, fmaf(hv.w,w3.w, acc[j][3]))));
    }
  }
  float4 bc = *(const float4*)(b + c0);
  float4 pc = *(const float4*)(p + c0);
  int width = CG;   // <= 64 always (Fo <= 256)
  #pragma unroll
  for(int j=0;j<8;j++){
    int row = rb + r0 + j;
    float v0 = fmaxf(acc[j][0]+bc.x, 0.f);
    float v1 = fmaxf(acc[j][1]+bc.y, 0.f);
    float v2 = fmaxf(acc[j][2]+bc.z, 0.f);
    float v3 = fmaxf(acc[j][3]+bc.w, 0.f);
    if(row < n) *(float4*)(out + (size_t)row*Fo + c0) = make_float4(v0,v1,v2,v3);
    float sc = v0*pc.x + v1*pc.y + v2*pc.z + v3*pc.w;
    for(int o=width>>1; o; o>>=1) sc += __shfl_down(sc, o, width);
    if(colg==0 && row<n) score[row] = tanhf(sc * pn_sh);
  }
}

// ---------------- grid-wide two-level 16-bit top-k select (fine histograms only) ----------------
__global__ void hist_hi(const float* __restrict__ score, int n, int* __restrict__ fine){
  int T = gridDim.x*blockDim.x;
  int lane = threadIdx.x&63;
  for(int base=0; base<n; base+=T){
    int i = base + blockIdx.x*blockDim.x + threadIdx.x;
    bool act = i<n;
    unsigned key = act ? (ordf(score[i])>>16) : 0u;
    unsigned long long eq = __ballot(act);
    #pragma unroll
    for(int bit=0;bit<16;bit++){
      unsigned long long bb = __ballot(act && ((key>>bit)&1u));
      eq &= ((key>>bit)&1u) ? bb : ~bb;
    }
    if(act){
      int lead = __ffsll(eq)-1;
      if(lane==lead) atomicAdd(&fine[key], __popcll(eq));
    }
  }
}

// derive hi-bin in-block from completed hi fine histogram, then histogram lo 16 bits
__global__ void hist_lo(const float* __restrict__ score, int n, int k,
                        const int* __restrict__ fh, int* __restrict__ fine){
  int r1;
  unsigned hi = (unsigned)derive_level(fh, k, &r1);
  int T = gridDim.x*blockDim.x;
  int lane = threadIdx.x&63;
  for(int base=0; base<n; base+=T){
    int i = base + blockIdx.x*blockDim.x + threadIdx.x;
    unsigned o = (i<n) ? ordf(score[i]) : 0u;
    bool act = (i<n) && ((o>>16)==hi);
    unsigned key = o & 0xFFFFu;
    unsigned long long eq = __ballot(act);
    #pragma unroll
    for(int bit=0;bit<16;bit++){
      unsigned long long bb = __ballot(act && ((key>>bit)&1u));
      eq &= ((key>>bit)&1u) ? bb : ~bb;
    }
    if(act){
      int lead = __ffsll(eq)-1;
      if(lane==lead) atomicAdd(&fine[key], __popcll(eq));
    }
  }
}

// single block: (hi, rank) from fh, then exact 32-bit threshold + tie quota from fl
__global__ void find_thr(const int* __restrict__ fh, const int* __restrict__ fl,
                         int k, unsigned* __restrict__ out_thr, int* __restrict__ out_q){
  int r1, q;
  int hi = derive_level(fh, k, &r1);
  int lo = derive_level(fl, r1, &q);
  if(threadIdx.x==0){
    out_thr[0] = ((unsigned)hi<<16)|(unsigned)lo;
    out_q[0]   = q;
  }
}

// ---------------- selection compaction ----------------

__global__ void sel_blockcount(const float* __restrict__ score, int n,
                               const unsigned* __restrict__ thr,
                               int* __restrict__ blkGt, int* __restrict__ blkEq){
  int i = blockIdx.x*256 + threadIdx.x;
  unsigned vthr = thr[0];
  int gt=0, eq=0;
  if(i<n){ unsigned o=ordf(score[i]); gt = (o>vthr); eq = (o==vthr); }
  unsigned long long bg=__ballot(gt), be=__ballot(eq);
  __shared__ int sg[4], se[4];
  int lane=threadIdx.x&63, w=threadIdx.x>>6;
  if(lane==0){ sg[w]=__popcll(bg); se[w]=__popcll(be); }
  __syncthreads();
  if(threadIdx.x==0){
    int g=0,e=0;
    for(int j=0;j<4;j++){ g+=sg[j]; e+=se[j]; }
    blkGt[blockIdx.x]=g; blkEq[blockIdx.x]=e;
  }
}

// selects top-k; writes oldidx (new->old) AND composes the orig-space survival map;
// block prefix computed in-block from raw per-block counts (kernel-boundary safe)
__global__ void compact(const float* __restrict__ score, int n,
                        const unsigned* __restrict__ thr, const int* __restrict__ qp,
                        const int* __restrict__ blkGt, const int* __restrict__ blkEq,
                        int* __restrict__ oldidx, int* __restrict__ map,
                        const int* __restrict__ ofc, int* __restrict__ ofn, int is_l0){
  __shared__ int s_bg, s_be;
  {
    int pg=0, pe=0;
    for(int j=threadIdx.x; j<(int)blockIdx.x; j+=256){ pg+=blkGt[j]; pe+=blkEq[j]; }
    for(int o=32;o;o>>=1){ pg+=__shfl_down(pg,o,64); pe+=__shfl_down(pe,o,64); }
    __shared__ int sgp[4], sep[4];
    int lane=threadIdx.x&63, w=threadIdx.x>>6;
    if(lane==0){ sgp[w]=pg; sep[w]=pe; }
    __syncthreads();
    if(threadIdx.x==0){ s_bg=sgp[0]+sgp[1]+sgp[2]+sgp[3]; s_be=sep[0]+sep[1]+sep[2]+sep[3]; }
    __syncthreads();
  }
  int i = blockIdx.x*256 + threadIdx.x;
  unsigned vthr = thr[0];
  int q = qp[0];
  int gt=0, eq=0;
  if(i<n){ unsigned o=ordf(score[i]); gt=(o>vthr); eq=(o==vthr); }
  unsigned long long bg=__ballot(gt), be=__ballot(eq);
  int lane=threadIdx.x&63, w=threadIdx.x>>6;
  unsigned long long mask = lane ? (~0ull >> (64-lane)) : 0ull;
  int pg = __popcll(bg & mask), pe = __popcll(be & mask);
  __shared__ int sg[4], se[4];
  if(lane==63){ sg[w]=pg+gt; se[w]=pe+eq; }
  __syncthreads();
  int wg=0,we=0;
  for(int j=0;j<w;j++){ wg+=sg[j]; we+=se[j]; }
  if(i<n){
    int gtp = s_bg + wg + pg;
    int eqp = s_be + we + pe;
    int sel = gt || (eq && (eqp < q));
    int ov = is_l0 ? i : ofc[i];
    if(sel){
      int pos = gtp + (eqp < q ? eqp : q);  // rank among selected, by original index
      oldidx[pos]=i;
      map[ov]=pos;
      ofn[pos]=ov;
    } else map[ov]=-1;
  }
}

// ---------------- epilogue ----------------

__global__ void pool_kernel(const float* __restrict__ h, const float* __restrict__ sc,
                            const int* __restrict__ oldidx, int n, float* __restrict__ xc){
  int f = blockIdx.x;
  float mx = -3.402823466e38f, sm=0.f;
  for(int r=threadIdx.x; r<n; r+=blockDim.x){
    int od = oldidx[r];
    float v = h[(size_t)od*256+f]*sc[od];
    mx = fmaxf(mx,v); sm += v;
  }
  __shared__ float smx[4], ssm[4];
  for(int o=32;o;o>>=1){ mx=fmaxf(mx,__shfl_down(mx,o,64)); sm+=__shfl_down(sm,o,64); }
  int lane=threadIdx.x&63, w=threadIdx.x>>6;
  if(lane==0){ smx[w]=mx; ssm[w]=sm; }
  __syncthreads();
  if(threadIdx.x==0){
    for(int j=1;j<4;j++){ mx=fmaxf(mx,smx[j]); sm+=ssm[j]; }
    xc[f]=mx; xc[256+f]=sm/(float)n;
  }
}

__global__ void fc_kernel(const float* __restrict__ xc, const float* __restrict__ fcw,
                          const float* __restrict__ fcb, const float* __restrict__ fc2w,
                          const float* __restrict__ fc2b, float* __restrict__ out){
  __shared__ float x[512];
  for(int i=threadIdx.x;i<512;i+=256) x[i]=xc[i];
  __syncthreads();
  int j=threadIdx.x;
  float a=fcb[j];
  for(int i=0;i<512;i++) a = fmaf(x[i], fcw[(size_t)j*512+i], a);
  a = a>0.f ? a : 0.f;
  float v = a*fc2w[j];
  for(int o=32;o;o>>=1) v += __shfl_down(v,o,64);
  __shared__ float sv[4];
  int lane=threadIdx.x&63, w=threadIdx.x>>6;
  if(lane==0) sv[w]=v;
  __syncthreads();
  if(threadIdx.x==0) out[0]=sv[0]+sv[1]+sv[2]+sv[3]+fc2b[0];
}

extern "C" void kernel_launch(void* const* d_in, const int* in_sizes, int n_in,
                              void* d_out, int out_size, void* d_ws, size_t ws_size,
                              hipStream_t stream) {
  const float* x   = (const float*)d_in[0];
  const int*   ei  = (const int*)d_in[1];
  const float* Wm[4] = {(const float*)d_in[2],(const float*)d_in[5],(const float*)d_in[8],(const float*)d_in[11]};
  const float* bv[4] = {(const float*)d_in[3],(const float*)d_in[6],(const float*)d_in[9],(const float*)d_in[12]};
  const float* pv[4] = {(const float*)d_in[4],(const float*)d_in[7],(const float*)d_in[10],(const float*)d_in[13]};
  const float* fcw  = (const float*)d_in[14];
  const float* fcb  = (const float*)d_in[15];
  const float* fc2w = (const float*)d_in[16];
  const float* fc2b = (const float*)d_in[17];

  char* base = (char*)d_ws; size_t off=0;
  auto alloc = [&](size_t bytes)->void*{
    void* p = base + off; off += (bytes + 511) & ~(size_t)511; return p;
  };
  int*   csr0   = (int*)  alloc((size_t)163842*CAP*4);
  int*   csr1   = (int*)  alloc((size_t)81921*CAP*4);
  int*   csr2   = (int*)  alloc((size_t)40961*CAP*4);
  int*   csr3   = (int*)  alloc((size_t)20481*CAP*4);
  float* score  = (float*)alloc((size_t)NV*4);
  int*   oldidx = (int*)  alloc((size_t)NV*4);
  int*   map    = (int*)  alloc((size_t)NV*4);   // orig-node -> current-layer idx (or -1)
  int*   ofA    = (int*)  alloc((size_t)NV*4);   // layer idx -> orig node, ping
  int*   ofB    = (int*)  alloc((size_t)NV*4);   // pong
  float* g      = (float*)alloc((size_t)2621568*4);
  float* hfull  = (float*)alloc((size_t)5243136*4);
  int*   blkGt  = (int*)  alloc(4096);
  int*   blkEq  = (int*)  alloc(4096);
  unsigned* thr = (unsigned*)alloc(64);
  int*   qv     = (int*)  alloc(64);
  float* xc     = (float*)alloc(2048);
  // ---- zero-init region (ONE memset: per-layer fine histograms + degree arrays) ----
  size_t zero_start = off;
  int*   ghist  = (int*)  alloc((size_t)4*2*65536*4); // per layer: fh, fl
  int*   deg0   = (int*)  alloc((size_t)163842*4);
  int*   deg1   = (int*)  alloc((size_t)81921*4);
  int*   deg2   = (int*)  alloc((size_t)40961*4);
  int*   deg3   = (int*)  alloc((size_t)20481*4);
  size_t zero_len = off - zero_start;
  if (off > ws_size) return;

  hipMemsetAsync(base + zero_start, 0, zero_len, stream);

  const int ns[5]   = {163842, 81921, 40961, 20481, 10241};
  const int dims[5] = {4, 32, 64, 128, 256};
  const int foshf[4]= {5, 6, 7, 8};     // log2(Fo)
  const int qshf[4] = {0, 3, 4, 5};     // log2(Fi/4)
  int* degs[4] = {deg0, deg1, deg2, deg3};
  int* csrs[4] = {csr0, csr1, csr2, csr3};

  const float* hprev = x;   // unused for l==0 path
  for(int l=0;l<4;l++){
    int n=ns[l], k=ns[l+1], Fi=dims[l], Fo=dims[l+1];
    int nb = (n+255)/256;
    int* fh = ghist + (size_t)l*2*65536;
    int* fl = fh + 65536;
    const int* ofc = (l&1) ? ofA : ofB;   // written by previous layer's compact
    int*       ofn = (l&1) ? ofB : ofA;
    // ---- CSR (fixed capacity; l>0 built by previous csr_build_next) ----
    if(l==0) csr_fill0<<<NBE2,256,0,stream>>>(ei, deg0, csr0);
    // ---- aggregation ----
    long long nq = (long long)n << qshf[l];
    unsigned ggrid = (unsigned)((nq+255)/256);
    if(l==0)
      csr_gather4<<<ggrid,256,0,stream>>>(x, degs[0], csrs[0], g, n, Fi, qshf[0]);
    else
      csr_gather4_ind<<<ggrid,256,0,stream>>>(hprev, score, oldidx, degs[l], csrs[l], g, n, Fi, qshf[l]);
    // ---- LDS + register tiled fused dense + score ----
    int BM = 8192 >> foshf[l];
    unsigned mgrid = (unsigned)((n + BM - 1) / BM);
    matmul_relu_score_t<<<mgrid,256,0,stream>>>(g, Wm[l], bv[l], pv[l], hfull, score,
                                                n, Fi, Fo, foshf[l], BM, qshf[l]);
    // ---- top-k selection (two-level 16-bit; standalone hists at 128 blocks) ----
    hist_hi<<<128,256,0,stream>>>(score, n, fh);
    hist_lo<<<128,256,0,stream>>>(score, n, k, fh, fl);
    find_thr<<<1,256,0,stream>>>(fh, fl, k, thr, qv);
    sel_blockcount<<<nb,256,0,stream>>>(score, n, thr, blkGt, blkEq);
    compact<<<nb,256,0,stream>>>(score, n, thr, qv, blkGt, blkEq,
                                 oldidx, map, ofc, ofn, (l==0)?1:0);
    // ---- next-layer CSR straight from original edges through composed map ----
    if(l<3) csr_build_next<<<NBE2,256,0,stream>>>(ei, map, degs[l+1], csrs[l+1]);
    hprev = hfull;
  }

  pool_kernel<<<256,256,0,stream>>>(hfull, score, oldidx, ns[4], xc);
  fc_kernel<<<1,256,0,stream>>>(xc, fcw, fcb, fc2w, fc2b, (float*)d_out);
}